// Round 4
// baseline (63.530 us; speedup 1.0000x reference)
//
#include <hip/hip_runtime.h>

typedef float vf4 __attribute__((ext_vector_type(4)));

// Phase 1: out[b, item, f] = emb_weight[item, f] for all b.
// One thread per OUTPUT float4, linear write order (single sequential store
// stream, like the 6.9 TB/s harness fill). emb re-reads for b>0 hit the
// 256 MB Infinity Cache (emb is 25.6 MB), so HBM read traffic stays ~26 MB.
__global__ void fill_bcast(const vf4* __restrict__ emb,
                           vf4* __restrict__ out,
                           int total4 /* B*ITEMS*FEAT/4 */,
                           int n4     /* ITEMS*FEAT/4 */) {
    int idx = blockIdx.x * blockDim.x + threadIdx.x;
    if (idx >= total4) return;
    int r = idx % n4;   // emb float4 index
    out[idx] = emb[r];
}

// Phase 2: for each flat node i (graph b), item = nodes[i]:
//   out[b, item, :] = (1 - alpha[item]) * emb[item, :] + alpha[item] * nodes_output[i, :]
// One thread per float4 of a row (FEAT/4 threads per node).
__global__ void scatter_upd(const vf4* __restrict__ nodes_out,
                            const vf4* __restrict__ emb,
                            const float* __restrict__ alpha,
                            const int* __restrict__ nodes,
                            const int* __restrict__ ptr,
                            vf4* __restrict__ out,
                            int n_nodes, int B, int feat4, size_t items_feat4) {
    int gid = blockIdx.x * blockDim.x + threadIdx.x;
    int i = gid / feat4;
    int f = gid - i * feat4;
    if (i >= n_nodes) return;

    int item = nodes[i];
    // batch id: ptr[b] <= i < ptr[b+1]  (B is tiny; ptr is scalar-cached)
    int b = 0;
    while (b + 1 < B && i >= ptr[b + 1]) ++b;

    float a = alpha[item];
    vf4 e = emb[(size_t)item * (size_t)feat4 + (size_t)f];
    vf4 x = nodes_out[(size_t)i * (size_t)feat4 + (size_t)f];
    vf4 r = (1.0f - a) * e + a * x;
    out[(size_t)b * items_feat4 + (size_t)item * (size_t)feat4 + (size_t)f] = r;
}

extern "C" void kernel_launch(void* const* d_in, const int* in_sizes, int n_in,
                              void* d_out, int out_size, void* d_ws, size_t ws_size,
                              hipStream_t stream) {
    const float* nodes_output = (const float*)d_in[0];   // [n_nodes, FEAT]
    const float* emb_weight   = (const float*)d_in[1];   // [ITEMS, FEAT]
    const float* alpha        = (const float*)d_in[2];   // [ITEMS, 1]
    const int*   nodes        = (const int*)d_in[3];     // [n_nodes]
    const int*   ptr          = (const int*)d_in[4];     // [B+1]

    const int n_nodes = in_sizes[3];
    const int items   = in_sizes[2];
    const int feat    = in_sizes[0] / n_nodes;   // 64
    const int B       = in_sizes[4] - 1;         // 8
    const int feat4   = feat / 4;                // 16
    const int n4      = items * feat4;           // ITEMS*FEAT/4 = 1.6M
    const int total4  = B * n4;                  // 12.8M output float4s
    const size_t items_feat4 = (size_t)items * (size_t)feat4;

    float* out = (float*)d_out;

    // Phase 1: broadcast emb_weight into every batch slice (linear writes).
    {
        int threads = 256;
        int blocks = (total4 + threads - 1) / threads;
        fill_bcast<<<blocks, threads, 0, stream>>>(
            (const vf4*)emb_weight, (vf4*)out, total4, n4);
    }
    // Phase 2: scatter gated updates (runs after fill; same stream).
    {
        int total = n_nodes * feat4;             // 65536
        int threads = 256;
        int blocks = (total + threads - 1) / threads;
        scatter_upd<<<blocks, threads, 0, stream>>>(
            (const vf4*)nodes_output, (const vf4*)emb_weight, alpha,
            nodes, ptr, (vf4*)out,
            n_nodes, B, feat4, items_feat4);
    }
}

// Round 5
// 43.800 us; speedup vs baseline: 1.4505x; 1.4505x over previous
//
#include <hip/hip_runtime.h>

typedef float vf4 __attribute__((ext_vector_type(4)));

// Phase 1: out[b, item, f] = emb_weight[item, f] for all b (B=8 compile-time).
// Each thread handles UNROLL consecutive float4s of emb: issue both loads,
// then 16 independent stores (read-once, 8-stream write — round-1 structure).
template <int B>
__global__ __launch_bounds__(256) void fill_bcast(const vf4* __restrict__ emb,
                                                  vf4* __restrict__ out,
                                                  int n4 /* ITEMS*FEAT/4 */) {
    int idx = (blockIdx.x * blockDim.x + threadIdx.x) * 2;
    if (idx + 1 < n4) {
        vf4 v0 = emb[idx];
        vf4 v1 = emb[idx + 1];
        #pragma unroll
        for (int b = 0; b < B; ++b) {
            size_t base = (size_t)b * (size_t)n4 + (size_t)idx;
            out[base] = v0;
            out[base + 1] = v1;
        }
    } else if (idx < n4) {
        vf4 v0 = emb[idx];
        #pragma unroll
        for (int b = 0; b < B; ++b)
            out[(size_t)b * (size_t)n4 + (size_t)idx] = v0;
    }
}

// Generic-B fallback (runtime B), same structure.
__global__ void fill_bcast_gen(const vf4* __restrict__ emb,
                               vf4* __restrict__ out,
                               int n4, int B) {
    int idx = blockIdx.x * blockDim.x + threadIdx.x;
    if (idx >= n4) return;
    vf4 v = emb[idx];
    for (int b = 0; b < B; ++b)
        out[(size_t)b * (size_t)n4 + (size_t)idx] = v;
}

// Phase 2: for each flat node i (graph b), item = nodes[i]:
//   out[b, item, :] = (1 - alpha[item]) * emb[item, :] + alpha[item] * nodes_output[i, :]
__global__ void scatter_upd(const vf4* __restrict__ nodes_out,
                            const vf4* __restrict__ emb,
                            const float* __restrict__ alpha,
                            const int* __restrict__ nodes,
                            const int* __restrict__ ptr,
                            vf4* __restrict__ out,
                            int n_nodes, int B, int feat4, size_t items_feat4) {
    int gid = blockIdx.x * blockDim.x + threadIdx.x;
    int i = gid / feat4;
    int f = gid - i * feat4;
    if (i >= n_nodes) return;

    int item = nodes[i];
    int b = 0;
    while (b + 1 < B && i >= ptr[b + 1]) ++b;

    float a = alpha[item];
    vf4 e = emb[(size_t)item * (size_t)feat4 + (size_t)f];
    vf4 x = nodes_out[(size_t)i * (size_t)feat4 + (size_t)f];
    vf4 r = (1.0f - a) * e + a * x;
    out[(size_t)b * items_feat4 + (size_t)item * (size_t)feat4 + (size_t)f] = r;
}

extern "C" void kernel_launch(void* const* d_in, const int* in_sizes, int n_in,
                              void* d_out, int out_size, void* d_ws, size_t ws_size,
                              hipStream_t stream) {
    const float* nodes_output = (const float*)d_in[0];   // [n_nodes, FEAT]
    const float* emb_weight   = (const float*)d_in[1];   // [ITEMS, FEAT]
    const float* alpha        = (const float*)d_in[2];   // [ITEMS, 1]
    const int*   nodes        = (const int*)d_in[3];     // [n_nodes]
    const int*   ptr          = (const int*)d_in[4];     // [B+1]

    const int n_nodes = in_sizes[3];
    const int items   = in_sizes[2];
    const int feat    = in_sizes[0] / n_nodes;   // 64
    const int B       = in_sizes[4] - 1;         // 8
    const int feat4   = feat / 4;                // 16
    const int n4      = items * feat4;           // ITEMS*FEAT/4 = 1.6M
    const size_t items_feat4 = (size_t)items * (size_t)feat4;

    float* out = (float*)d_out;

    // Phase 1: broadcast emb_weight into every batch slice.
    if (B == 8) {
        int threads = 256;
        int n_pairs = (n4 + 1) / 2;
        int blocks = (n_pairs + threads - 1) / threads;
        fill_bcast<8><<<blocks, threads, 0, stream>>>(
            (const vf4*)emb_weight, (vf4*)out, n4);
    } else {
        int threads = 256;
        int blocks = (n4 + threads - 1) / threads;
        fill_bcast_gen<<<blocks, threads, 0, stream>>>(
            (const vf4*)emb_weight, (vf4*)out, n4, B);
    }
    // Phase 2: scatter gated updates (runs after fill; same stream).
    {
        int total = n_nodes * feat4;             // 65536
        int threads = 256;
        int blocks = (total + threads - 1) / threads;
        scatter_upd<<<blocks, threads, 0, stream>>>(
            (const vf4*)nodes_output, (const vf4*)emb_weight, alpha,
            nodes, ptr, (vf4*)out,
            n_nodes, B, feat4, items_feat4);
    }
}

// Round 6
// 41.071 us; speedup vs baseline: 1.5468x; 1.0664x over previous
//
#include <hip/hip_runtime.h>

// Best measured structure (round 1, 40.8 us): one thread per emb float4,
// read once into registers, 8 coalesced stores (one per batch slice).
// All deviations regressed: nontemporal stores +10%, linear-write inversion
// +55% (L3 read amplification), 2x unroll +7% (less TLP).

__global__ void fill_bcast(const float4* __restrict__ emb,
                           float4* __restrict__ out,
                           int n4 /* ITEMS*FEAT/4 */, int B) {
    int idx = blockIdx.x * blockDim.x + threadIdx.x;
    if (idx >= n4) return;
    float4 v = emb[idx];
    for (int b = 0; b < B; ++b) {
        out[(size_t)b * (size_t)n4 + (size_t)idx] = v;
    }
}

// Phase 2: for each flat node i (graph b), item = nodes[i]:
//   out[b, item, :] = (1 - alpha[item]) * emb[item, :] + alpha[item] * nodes_output[i, :]
// One thread per float4 of a row (FEAT/4 threads per node).
__global__ void scatter_upd(const float4* __restrict__ nodes_out,
                            const float4* __restrict__ emb,
                            const float* __restrict__ alpha,
                            const int* __restrict__ nodes,
                            const int* __restrict__ ptr,
                            float4* __restrict__ out,
                            int n_nodes, int B, int feat4, size_t items_feat4) {
    int gid = blockIdx.x * blockDim.x + threadIdx.x;
    int i = gid / feat4;
    int f = gid - i * feat4;
    if (i >= n_nodes) return;

    int item = nodes[i];
    // batch id: ptr[b] <= i < ptr[b+1]  (B is tiny; ptr is scalar-cached)
    int b = 0;
    while (b + 1 < B && i >= ptr[b + 1]) ++b;

    float a = alpha[item];
    float4 e = emb[(size_t)item * (size_t)feat4 + (size_t)f];
    float4 x = nodes_out[(size_t)i * (size_t)feat4 + (size_t)f];
    float4 r;
    r.x = (1.0f - a) * e.x + a * x.x;
    r.y = (1.0f - a) * e.y + a * x.y;
    r.z = (1.0f - a) * e.z + a * x.z;
    r.w = (1.0f - a) * e.w + a * x.w;
    out[(size_t)b * items_feat4 + (size_t)item * (size_t)feat4 + (size_t)f] = r;
}

extern "C" void kernel_launch(void* const* d_in, const int* in_sizes, int n_in,
                              void* d_out, int out_size, void* d_ws, size_t ws_size,
                              hipStream_t stream) {
    const float* nodes_output = (const float*)d_in[0];   // [n_nodes, FEAT]
    const float* emb_weight   = (const float*)d_in[1];   // [ITEMS, FEAT]
    const float* alpha        = (const float*)d_in[2];   // [ITEMS, 1]
    const int*   nodes        = (const int*)d_in[3];     // [n_nodes]
    const int*   ptr          = (const int*)d_in[4];     // [B+1]

    const int n_nodes = in_sizes[3];
    const int items   = in_sizes[2];
    const int feat    = in_sizes[0] / n_nodes;   // 64
    const int B       = in_sizes[4] - 1;         // 8
    const int feat4   = feat / 4;                // 16
    const int n4      = items * feat4;           // ITEMS*FEAT/4 = 1.6M
    const size_t items_feat4 = (size_t)items * (size_t)feat4;

    float* out = (float*)d_out;

    // Phase 1: broadcast emb_weight into every batch slice.
    {
        int threads = 256;
        int blocks = (n4 + threads - 1) / threads;
        fill_bcast<<<blocks, threads, 0, stream>>>(
            (const float4*)emb_weight, (float4*)out, n4, B);
    }
    // Phase 2: scatter gated updates (runs after fill; same stream).
    {
        int total = n_nodes * feat4;             // 65536
        int threads = 256;
        int blocks = (total + threads - 1) / threads;
        scatter_upd<<<blocks, threads, 0, stream>>>(
            (const float4*)nodes_output, (const float4*)emb_weight, alpha,
            nodes, ptr, (float4*)out,
            n_nodes, B, feat4, items_feat4);
    }
}